// Round 5
// baseline (635.633 us; speedup 1.0000x reference)
//
#include <hip/hip_runtime.h>
#include <hip/hip_bf16.h>

// ---------- common helpers ----------
typedef __attribute__((ext_vector_type(8))) short short8;
typedef __attribute__((ext_vector_type(4))) float floatx4;

__device__ __forceinline__ ushort f2bf(float x) {
    unsigned u = __float_as_uint(x);
    unsigned r = (u + 0x7fffu + ((u >> 16) & 1u)) >> 16;
    return (ushort)r;
}
__device__ __forceinline__ float bf2f(ushort h) {
    return __uint_as_float(((unsigned)h) << 16);
}
__device__ __forceinline__ float fast_sigmoid(float x) {
    return 1.0f / (1.0f + __expf(-x));
}
__device__ __forceinline__ float fast_tanh(float x) {
    x = fminf(fmaxf(x, -15.0f), 15.0f);
    float e = __expf(2.0f * x);
    return (e - 1.0f) / (e + 1.0f);
}
__device__ __forceinline__ void load_lds16(const void* g, void* l) {
    __builtin_amdgcn_global_load_lds(
        (__attribute__((address_space(1))) void*)(g),
        (__attribute__((address_space(3))) void*)(l),
        16, 0, 0);
}

// ---------- swizzled LDS tile: units of 8 rows x 64 cols (1 KB) ----------
// Physical: unit row r holds logical 16B-chunk lc at chunk slot lc^r (conflict-free, verified:
// SQ_LDS_BANK_CONFLICT=0). Staging lane L = r*8+cp fetches logical chunk cp^r.
__device__ __forceinline__ void stage_unit(const ushort* grow0, int ld, ushort* lds_unit) {
    const int lane = threadIdx.x & 63;
    const int r = lane >> 3;
    const int c = (lane & 7) ^ r;
    load_lds16(grow0 + (size_t)r * ld + c * 8, lds_unit);
}
__device__ __forceinline__ short8 lds_read8(const ushort* buf, int R, int c_el) {
    const int idx = ((R >> 3) << 9) + ((R & 7) << 6) + ((((c_el >> 3) ^ (R & 7))) << 3);
    return *(const short8*)(buf + idx);
}

// ---------- fp32 -> bf16: one merged kernel for obs + 4 weight tensors ----------
__global__ __launch_bounds__(256) void cvt_all(
    const float* __restrict__ s0, ushort* __restrict__ d0,   // obs   4194304 float4
    const float* __restrict__ s1, ushort* __restrict__ d1,   // W_ds  1048576
    const float* __restrict__ s2, ushort* __restrict__ d2,   // W_pol  131072
    const float* __restrict__ s3, ushort* __restrict__ d3,   // W_ih   196608
    const float* __restrict__ s4, ushort* __restrict__ d4) { // W_hh   196608
    int i = blockIdx.x * 256 + threadIdx.x;
    const float* s;
    ushort* d;
    int j;
    if (i < 4194304)      { s = s0; d = d0; j = i; }
    else if (i < 5242880) { s = s1; d = d1; j = i - 4194304; }
    else if (i < 5373952) { s = s2; d = d2; j = i - 5242880; }
    else if (i < 5570560) { s = s3; d = d3; j = i - 5373952; }
    else if (i < 5767168) { s = s4; d = d4; j = i - 5570560; }
    else return;
    const float4 v = ((const float4*)s)[j];
    ushort4 o;
    o.x = f2bf(v.x); o.y = f2bf(v.y); o.z = f2bf(v.z); o.w = f2bf(v.w);
    ((ushort4*)d)[j] = o;
}

// ---------- plain fp32 -> bf16 (for nbr, converted late into split-K scratch) ----------
__global__ __launch_bounds__(256) void cvt_f32_bf16(const float* __restrict__ src,
                                                    ushort* __restrict__ dst, int n4) {
    int i = blockIdx.x * blockDim.x + threadIdx.x;
    if (i >= n4) return;
    const float4 v = ((const float4*)src)[i];
    ushort4 o;
    o.x = f2bf(v.x); o.y = f2bf(v.y); o.z = f2bf(v.z); o.w = f2bf(v.w);
    ((ushort4*)dst)[i] = o;
}

// ---------- counting sort of rows by cnt descending ----------
// perm[sorted]=orig, inv[orig]=sorted, nact[t]=#rows with cnt>t.
__global__ __launch_bounds__(256) void sort_by_cnt(const int* __restrict__ cnt,
                                                   int* __restrict__ perm,
                                                   int* __restrict__ inv,
                                                   int* __restrict__ nact) {
    __shared__ int h[9];
    __shared__ int cur[9];
    const int tid = threadIdx.x;
    if (tid < 9) h[tid] = 0;
    __syncthreads();
    for (int i = tid; i < 4096; i += 256) atomicAdd(&h[cnt[i]], 1);
    __syncthreads();
    if (tid == 0) {
        int off = 0;
        for (int c = 8; c >= 0; --c) { cur[c] = off; off += h[c]; }
        for (int t = 0; t < 8; ++t) {
            int n = 0;
            for (int c = t + 1; c <= 8; ++c) n += h[c];
            nact[t] = n;
        }
    }
    __syncthreads();
    for (int i = tid; i < 4096; i += 256) {
        const int c = cnt[i];
        const int p = atomicAdd(&cur[c], 1);
        perm[p] = i;
        inv[i] = p;
    }
}

// ---------- GEMM: C[M,N] = A[M,K] * B[N,K]^T, BM=64, swizzled LDS ----------
// MODE 2: +bias, relu, store bf16 AND fp32 (KSPLIT must be 1); MAP: scatter C rows via row_map
// MODE 3: fp32 partial store (split-K), no bias/act
template <int MODE, int BN, int KSPLIT, bool MAP>
__global__ __launch_bounds__(256, 2) void gemm64(
    const ushort* __restrict__ A, int lda,
    const ushort* __restrict__ B, int ldb,
    const float* __restrict__ bias,
    const int* __restrict__ row_map,
    ushort* __restrict__ Cb, float* __restrict__ Cf, int ldc,
    int K, size_t part_stride) {
    __shared__ __attribute__((aligned(16))) ushort sA[64 * 64];
    __shared__ __attribute__((aligned(16))) ushort sB[BN * 64];

    constexpr int NJ = (BN + 63) / 64;  // 16-col tiles per wave (2 for BN=128, 1 for BN=64)
    constexpr int UB = BN / 32;         // B units per wave

    const int tid = threadIdx.x;
    const int lane = tid & 63;
    const int w = tid >> 6;
    const int m0 = blockIdx.y * 64;
    const int n0 = blockIdx.x * BN;
    const int wn = w * (16 * NJ);
    const int nl = lane & 15;

    const int Kper = K / KSPLIT;
    const int kbase = (KSPLIT > 1) ? blockIdx.z * Kper : 0;
    if (MODE == 3) Cf += (size_t)blockIdx.z * part_stride;

    floatx4 acc[4][NJ] = {};

    for (int k0 = kbase; k0 < kbase + Kper; k0 += 64) {
#pragma unroll
        for (int u = 0; u < 2; ++u) {
            const int ua = w * 2 + u;
            stage_unit(A + (size_t)(m0 + ua * 8) * lda + k0, lda, &sA[ua * 512]);
        }
#pragma unroll
        for (int u = 0; u < UB; ++u) {
            const int ub = w * UB + u;
            stage_unit(B + (size_t)(n0 + ub * 8) * ldb + k0, ldb, &sB[ub * 512]);
        }
        __syncthreads();  // drains vmcnt per HIP barrier semantics
#pragma unroll
        for (int kk = 0; kk < 2; ++kk) {
            const int cb = kk * 32 + (lane >> 4) * 8;
            short8 a[4], b[NJ];
#pragma unroll
            for (int i = 0; i < 4; ++i) a[i] = lds_read8(sA, i * 16 + nl, cb);
#pragma unroll
            for (int j = 0; j < NJ; ++j) b[j] = lds_read8(sB, wn + j * 16 + nl, cb);
#pragma unroll
            for (int i = 0; i < 4; ++i)
#pragma unroll
                for (int j = 0; j < NJ; ++j)
                    acc[i][j] = __builtin_amdgcn_mfma_f32_16x16x32_bf16(a[i], b[j], acc[i][j], 0, 0, 0);
        }
        __syncthreads();
    }

    // epilogue: C/D layout row=(lane>>4)*4+reg, col=lane&15
    const int ml = (lane >> 4) * 4;
#pragma unroll
    for (int j = 0; j < NJ; ++j) {
        const int n = n0 + wn + j * 16 + nl;
        float bv = 0.0f;
        if (MODE == 2) bv = bias[n];
#pragma unroll
        for (int i = 0; i < 4; ++i) {
            const int mbase = m0 + i * 16 + ml;
#pragma unroll
            for (int r = 0; r < 4; ++r) {
                float v = acc[i][j][r];
                const int mr = mbase + r;
                const int orow = MAP ? row_map[mr] : mr;
                const size_t off = (size_t)orow * ldc + n;
                if (MODE == 2) {
                    v += bv; v = fmaxf(v, 0.0f);
                    Cb[off] = f2bf(v);
                    Cf[off] = v;
                } else {
                    Cf[off] = v;
                }
            }
        }
    }
}

// ---------- split-K combine: enc = relu(p0 + p1 + bias) -> bf16 ----------
__global__ __launch_bounds__(256) void combine_relu(const float* __restrict__ p0,
                                                    const float* __restrict__ p1,
                                                    const float* __restrict__ bias,
                                                    ushort* __restrict__ ob, int n4) {
    int i = blockIdx.x * blockDim.x + threadIdx.x;
    if (i >= n4) return;
    const float4 a = ((const float4*)p0)[i];
    const float4 b = ((const float4*)p1)[i];
    const int col = (i * 4) & 1023;
    const float4 bs = *(const float4*)(bias + col);
    ushort4 o;
    o.x = f2bf(fmaxf(a.x + b.x + bs.x, 0.f));
    o.y = f2bf(fmaxf(a.y + b.y + bs.y, 0.f));
    o.z = f2bf(fmaxf(a.z + b.z + bs.z, 0.f));
    o.w = f2bf(fmaxf(a.w + b.w + bs.w, 0.f));
    ((ushort4*)ob)[i] = o;
}

// ---------- fused GRU step: NO LDS, NO barriers, register MFMA fragments from L2 ----------
// All operands (Wih/Whh 3 MB, Hin 4 MB, X slice 4 MB) are L2-resident. Each MFMA fragment's
// per-lane 16B is loaded DIRECTLY from global in native layout:
//   A-frag: lane l -> row (l&15), k-bytes (l>>4)*16; lanes {nl,nl+16,nl+32,nl+48} cover 64
//   contiguous bytes of one row -> perfect 64B segments.
// K-advance (c*64B, c=0..15) folds into the offset: immediate -> zero address math in loop.
// Removes per-64k: 28 ds_read_b128 (~336cy), 16 global_load_lds, 2 vmcnt-drain barriers.
// MFMA sequence and order identical to the verified round-0 kernel -> bit-identical output.
// Waves fully independent: latency hidden by 8-12 waves/CU TLP, never by a barrier.
__global__ __launch_bounds__(256) void gru_step(
    const ushort* __restrict__ Xall,  // nbr_b (orig row-major, row stride 4096), +t*512
    const ushort* __restrict__ Hin,   // [4096,512] bf16, sorted space
    const ushort* __restrict__ Wih,   // [1536,512] bf16
    const ushort* __restrict__ Whh,   // [1536,512] bf16
    const float* __restrict__ bih, const float* __restrict__ bhh,
    const int* __restrict__ perm, const int* __restrict__ nact,
    float* __restrict__ hf, ushort* __restrict__ Hout, int t) {
    const int tid = threadIdx.x;
    const int lane = tid & 63;
    const int w = tid >> 6;          // col quarter 0..3
    const int s = blockIdx.x;        // col slab 0..7
    const int m0 = blockIdx.y * 64;  // sorted batch-row base
    const int na = nact[t];
    if (m0 >= na) return;            // fully inactive panel: rows never read downstream

    const int nl = lane & 15;
    const int kq = (lane >> 4) * 8;  // fragment k sub-offset (elements)
    const int ml = (lane >> 4) * 4;
    const int col = s * 64 + w * 16 + nl;  // this lane's h column

    // A bases: 4 m-tiles, row = m0 + i*16 + nl (X gathered via perm)
    const ushort* xa[4];
    const ushort* ha[4];
#pragma unroll
    for (int i = 0; i < 4; ++i) {
        const int srow = m0 + i * 16 + nl;
        xa[i] = Xall + (size_t)perm[srow] * 4096 + t * 512 + kq;
        ha[i] = Hin + (size_t)srow * 512 + kq;
    }
    // B bases: 6 gate rows = col, col+512, col+1024 of Wih / Whh
    const ushort* bi0 = Wih + (size_t)col * 512 + kq;
    const ushort* bi1 = Wih + (size_t)(512 + col) * 512 + kq;
    const ushort* bi2 = Wih + (size_t)(1024 + col) * 512 + kq;
    const ushort* bh0 = Whh + (size_t)col * 512 + kq;
    const ushort* bh1 = Whh + (size_t)(512 + col) * 512 + kq;
    const ushort* bh2 = Whh + (size_t)(1024 + col) * 512 + kq;

    // acc init with biases (depends only on column)
    floatx4 accr[4], accz[4], accn[4], acch[4];
    {
        const float br_ = bih[col] + bhh[col];
        const float bz_ = bih[512 + col] + bhh[512 + col];
        const float bn_i = bih[1024 + col];
        const float bn_h = bhh[1024 + col];
        const floatx4 vr = {br_, br_, br_, br_};
        const floatx4 vz = {bz_, bz_, bz_, bz_};
        const floatx4 vi = {bn_i, bn_i, bn_i, bn_i};
        const floatx4 vh = {bn_h, bn_h, bn_h, bn_h};
#pragma unroll
        for (int i = 0; i < 4; ++i) { accr[i] = vr; accz[i] = vz; accn[i] = vi; acch[i] = vh; }
    }

#pragma unroll
    for (int c = 0; c < 16; ++c) {   // k = c*32 .. +31; byte offset c*64 is an imm
        const int ko = c * 32;
        short8 ax[4], ah[4];
#pragma unroll
        for (int i = 0; i < 4; ++i) {
            ax[i] = *(const short8*)(xa[i] + ko);
            ah[i] = *(const short8*)(ha[i] + ko);
        }
        const short8 bir = *(const short8*)(bi0 + ko);
        const short8 biz = *(const short8*)(bi1 + ko);
        const short8 bin = *(const short8*)(bi2 + ko);
        const short8 bhr = *(const short8*)(bh0 + ko);
        const short8 bhz = *(const short8*)(bh1 + ko);
        const short8 bhn = *(const short8*)(bh2 + ko);
#pragma unroll
        for (int i = 0; i < 4; ++i) {
            accr[i] = __builtin_amdgcn_mfma_f32_16x16x32_bf16(ax[i], bir, accr[i], 0, 0, 0);
            accr[i] = __builtin_amdgcn_mfma_f32_16x16x32_bf16(ah[i], bhr, accr[i], 0, 0, 0);
            accz[i] = __builtin_amdgcn_mfma_f32_16x16x32_bf16(ax[i], biz, accz[i], 0, 0, 0);
            accz[i] = __builtin_amdgcn_mfma_f32_16x16x32_bf16(ah[i], bhz, accz[i], 0, 0, 0);
            accn[i] = __builtin_amdgcn_mfma_f32_16x16x32_bf16(ax[i], bin, accn[i], 0, 0, 0);
            acch[i] = __builtin_amdgcn_mfma_f32_16x16x32_bf16(ah[i], bhn, acch[i], 0, 0, 0);
        }
    }

    // epilogue: gates + positional mask (sorted rows); C/D row=(lane>>4)*4+reg, col=lane&15
    const bool full = (m0 + 64 <= na);
#pragma unroll
    for (int i = 0; i < 4; ++i) {
#pragma unroll
        for (int r4 = 0; r4 < 4; ++r4) {
            const int row = m0 + i * 16 + ml + r4;
            const float rg = fast_sigmoid(accr[i][r4]);
            const float zg = fast_sigmoid(accz[i][r4]);
            const float ng = fast_tanh(accn[i][r4] + rg * acch[i][r4]);
            const size_t off = (size_t)row * 512 + col;
            const float ho = hf[off];
            const bool act = full || (row < na);
            const float hv = act ? ((1.0f - zg) * ng + zg * ho) : ho;
            hf[off] = hv;
            if (t < 7) Hout[off] = f2bf(hv);
        }
    }
}

// ---------- v_net: tanh(enc @ W_v^T + b_v), one wave per row (original space) ----------
__global__ __launch_bounds__(256) void v_kernel(const ushort* __restrict__ enc,
                                                const float* __restrict__ Wv,
                                                const float* __restrict__ bv,
                                                float* __restrict__ out) {
    const int row = blockIdx.x * 4 + (threadIdx.x >> 6);
    const int lane = threadIdx.x & 63;
    const ushort* e = enc + (size_t)row * 1024;
    float s = 0.0f;
#pragma unroll
    for (int i = 0; i < 16; ++i) {
        int k = lane + i * 64;
        s += bf2f(e[k]) * Wv[k];
    }
#pragma unroll
    for (int off = 32; off; off >>= 1) s += __shfl_down(s, off, 64);
    if (lane == 0) out[row] = fast_tanh(s + bv[0]);
}

// ---------- to_probs: softmax(relu(h @ W_pr^T + b_pr)); h in sorted space ----------
__global__ __launch_bounds__(256) void probs_kernel(const float* __restrict__ h,
                                                    const float* __restrict__ Wpr,
                                                    const float* __restrict__ bpr,
                                                    const int* __restrict__ perm,
                                                    float* __restrict__ out) {
    const int srow = blockIdx.x * 4 + (threadIdx.x >> 6);
    const int lane = threadIdx.x & 63;
    const float* hr = h + (size_t)srow * 512;
    float p0 = 0.f, p1 = 0.f, p2 = 0.f;
#pragma unroll
    for (int i = 0; i < 8; ++i) {
        int k = lane + i * 64;
        float x = hr[k];
        p0 += x * Wpr[k];
        p1 += x * Wpr[512 + k];
        p2 += x * Wpr[1024 + k];
    }
#pragma unroll
    for (int off = 32; off; off >>= 1) {
        p0 += __shfl_down(p0, off, 64);
        p1 += __shfl_down(p1, off, 64);
        p2 += __shfl_down(p2, off, 64);
    }
    if (lane == 0) {
        const int orow = perm[srow];
        p0 = fmaxf(p0 + bpr[0], 0.f);
        p1 = fmaxf(p1 + bpr[1], 0.f);
        p2 = fmaxf(p2 + bpr[2], 0.f);
        float m = fmaxf(p0, fmaxf(p1, p2));
        float e0 = __expf(p0 - m), e1 = __expf(p1 - m), e2 = __expf(p2 - m);
        float inv = 1.0f / (e0 + e1 + e2);
        out[orow * 3 + 0] = e0 * inv;
        out[orow * 3 + 1] = e1 * inv;
        out[orow * 3 + 2] = e2 * inv;
    }
}

extern "C" void kernel_launch(void* const* d_in, const int* in_sizes, int n_in,
                              void* d_out, int out_size, void* d_ws, size_t ws_size,
                              hipStream_t stream) {
    const float* obs   = (const float*)d_in[0];   // [4096,4096]
    const float* nbr   = (const float*)d_in[1];   // [4096,8,512]
    const int*   cnt   = (const int*)d_in[2];     // [4096]
    const float* W_ds  = (const float*)d_in[3];   // [1024,4096]
    const float* b_ds  = (const float*)d_in[4];
    const float* W_pol = (const float*)d_in[5];   // [512,1024]
    const float* b_pol = (const float*)d_in[6];
    const float* W_v   = (const float*)d_in[7];   // [1,1024]
    const float* b_v   = (const float*)d_in[8];
    const float* W_ih  = (const float*)d_in[9];   // [1536,512]
    const float* b_ih  = (const float*)d_in[10];
    const float* W_hh  = (const float*)d_in[11];  // [1536,512]
    const float* b_hh  = (const float*)d_in[12];
    const float* W_pr  = (const float*)d_in[13];  // [3,512]
    const float* b_pr  = (const float*)d_in[14];
    float* out = (float*)d_out;  // [4096*3 probs][4096 state_vals]

    // workspace layout (round-0 footprint, ~100 MB + 32 KB)
    ushort* obs_b  = (ushort*)d_ws;              // 32 MB
    ushort* Wds_b  = obs_b + 16777216;           // 8 MB
    ushort* Wpol_b = Wds_b + 4194304;            // 1 MB
    ushort* Wih_b  = Wpol_b + 524288;            // 1.5 MB
    ushort* Whh_b  = Wih_b + 786432;             // 1.5 MB
    ushort* enc_b  = Whh_b + 786432;             // 8 MB
    ushort* h_b0   = enc_b + 4194304;            // 4 MB
    ushort* h_b1   = h_b0 + 2097152;             // 4 MB
    float*  h_f    = (float*)(h_b1 + 2097152);   // 8 MB
    float*  part   = h_f + 2097152;              // 32 MB split-K scratch, then nbr_b
    ushort* nbr_b  = (ushort*)part;              // aliases part AFTER combine
    int*    perm   = (int*)(part + 8388608);     // 4096
    int*    inv    = perm + 4096;                // 4096
    int*    nact   = inv + 4096;                 // 16

    // 0) sort rows by neighbor count (descending)
    sort_by_cnt<<<1, 256, 0, stream>>>(cnt, perm, inv, nact);

    // 1) one merged cvt for obs + all weights
    cvt_all<<<22528, 256, 0, stream>>>(obs, obs_b, W_ds, Wds_b, W_pol, Wpol_b,
                                       W_ih, Wih_b, W_hh, Whh_b);

    // 2) enc = relu(obs @ W_ds^T + b_ds), BN=128 split-K=2 -> 1024 blocks (~4/CU)
    gemm64<3, 128, 2, false><<<dim3(8, 64, 2), 256, 0, stream>>>(
        obs_b, 4096, Wds_b, 4096, nullptr, nullptr, nullptr, part, 1024, 4096, 4194304);
    combine_relu<<<4096, 256, 0, stream>>>(part, part + 4194304, b_ds, enc_b, 1048576);

    // 3) nbr -> bf16 into the (now free) split-K scratch
    cvt_f32_bf16<<<16384, 256, 0, stream>>>(nbr, nbr_b, 4194304);

    // 4) pol = relu(enc @ W_pol^T + b_pol) scattered into sorted space (h_b0 + h_f)
    gemm64<2, 64, 1, true><<<dim3(8, 64, 1), 256, 0, stream>>>(
        enc_b, 1024, Wpol_b, 1024, b_pol, inv, h_b0, h_f, 512, 1024, 0);

    // 5) state_vals (original space)
    v_kernel<<<1024, 256, 0, stream>>>(enc_b, W_v, b_v, out + 12288);

    // 6) GRU: 8 fused steps, no-LDS register-fragment GEMM straight from L2
    for (int t = 0; t < 8; ++t) {
        const ushort* hin = (t & 1) ? h_b1 : h_b0;
        ushort* hout = (t & 1) ? h_b0 : h_b1;
        gru_step<<<dim3(8, 64), 256, 0, stream>>>(nbr_b, hin, Wih_b, Whh_b,
                                                  b_ih, b_hh, perm, nact, h_f, hout, t);
    }

    // 7) probs (sorted -> original scatter)
    probs_kernel<<<1024, 256, 0, stream>>>(h_f, W_pr, b_pr, perm, out);
}

// Round 6
// 443.390 us; speedup vs baseline: 1.4336x; 1.4336x over previous
//
#include <hip/hip_runtime.h>
#include <hip/hip_bf16.h>

// ---------- common helpers ----------
typedef __attribute__((ext_vector_type(8))) short short8;
typedef __attribute__((ext_vector_type(4))) float floatx4;

__device__ __forceinline__ ushort f2bf(float x) {
    unsigned u = __float_as_uint(x);
    unsigned r = (u + 0x7fffu + ((u >> 16) & 1u)) >> 16;
    return (ushort)r;
}
__device__ __forceinline__ float bf2f(ushort h) {
    return __uint_as_float(((unsigned)h) << 16);
}
__device__ __forceinline__ float fast_sigmoid(float x) {
    return 1.0f / (1.0f + __expf(-x));
}
__device__ __forceinline__ float fast_tanh(float x) {
    x = fminf(fmaxf(x, -15.0f), 15.0f);
    float e = __expf(2.0f * x);
    return (e - 1.0f) / (e + 1.0f);
}
__device__ __forceinline__ void load_lds16(const void* g, void* l) {
    __builtin_amdgcn_global_load_lds(
        (__attribute__((address_space(1))) void*)(g),
        (__attribute__((address_space(3))) void*)(l),
        16, 0, 0);
}

// ---------- swizzled LDS tile: units of 8 rows x 64 cols (1 KB) ----------
// Physical: unit row r holds logical 16B-chunk lc at chunk slot lc^r (conflict-free, verified:
// SQ_LDS_BANK_CONFLICT=0). Staging lane L = r*8+cp fetches logical chunk cp^r.
__device__ __forceinline__ void stage_unit(const ushort* grow0, int ld, ushort* lds_unit) {
    const int lane = threadIdx.x & 63;
    const int r = lane >> 3;
    const int c = (lane & 7) ^ r;
    load_lds16(grow0 + (size_t)r * ld + c * 8, lds_unit);
}
__device__ __forceinline__ short8 lds_read8(const ushort* buf, int R, int c_el) {
    const int idx = ((R >> 3) << 9) + ((R & 7) << 6) + ((((c_el >> 3) ^ (R & 7))) << 3);
    return *(const short8*)(buf + idx);
}

// ---------- fp32 -> bf16: one merged kernel for obs + 4 weight tensors ----------
__global__ __launch_bounds__(256) void cvt_all(
    const float* __restrict__ s0, ushort* __restrict__ d0,   // obs   4194304 float4
    const float* __restrict__ s1, ushort* __restrict__ d1,   // W_ds  1048576
    const float* __restrict__ s2, ushort* __restrict__ d2,   // W_pol  131072
    const float* __restrict__ s3, ushort* __restrict__ d3,   // W_ih   196608
    const float* __restrict__ s4, ushort* __restrict__ d4) { // W_hh   196608
    int i = blockIdx.x * 256 + threadIdx.x;
    const float* s;
    ushort* d;
    int j;
    if (i < 4194304)      { s = s0; d = d0; j = i; }
    else if (i < 5242880) { s = s1; d = d1; j = i - 4194304; }
    else if (i < 5373952) { s = s2; d = d2; j = i - 5242880; }
    else if (i < 5570560) { s = s3; d = d3; j = i - 5373952; }
    else if (i < 5767168) { s = s4; d = d4; j = i - 5570560; }
    else return;
    const float4 v = ((const float4*)s)[j];
    ushort4 o;
    o.x = f2bf(v.x); o.y = f2bf(v.y); o.z = f2bf(v.z); o.w = f2bf(v.w);
    ((ushort4*)d)[j] = o;
}

// ---------- plain fp32 -> bf16 (for nbr, converted late into split-K scratch) ----------
__global__ __launch_bounds__(256) void cvt_f32_bf16(const float* __restrict__ src,
                                                    ushort* __restrict__ dst, int n4) {
    int i = blockIdx.x * blockDim.x + threadIdx.x;
    if (i >= n4) return;
    const float4 v = ((const float4*)src)[i];
    ushort4 o;
    o.x = f2bf(v.x); o.y = f2bf(v.y); o.z = f2bf(v.z); o.w = f2bf(v.w);
    ((ushort4*)dst)[i] = o;
}

// ---------- counting sort of rows by cnt descending ----------
// perm[sorted]=orig, inv[orig]=sorted, nact[t]=#rows with cnt>t.
__global__ __launch_bounds__(256) void sort_by_cnt(const int* __restrict__ cnt,
                                                   int* __restrict__ perm,
                                                   int* __restrict__ inv,
                                                   int* __restrict__ nact) {
    __shared__ int h[9];
    __shared__ int cur[9];
    const int tid = threadIdx.x;
    if (tid < 9) h[tid] = 0;
    __syncthreads();
    for (int i = tid; i < 4096; i += 256) atomicAdd(&h[cnt[i]], 1);
    __syncthreads();
    if (tid == 0) {
        int off = 0;
        for (int c = 8; c >= 0; --c) { cur[c] = off; off += h[c]; }
        for (int t = 0; t < 8; ++t) {
            int n = 0;
            for (int c = t + 1; c <= 8; ++c) n += h[c];
            nact[t] = n;
        }
    }
    __syncthreads();
    for (int i = tid; i < 4096; i += 256) {
        const int c = cnt[i];
        const int p = atomicAdd(&cur[c], 1);
        perm[p] = i;
        inv[i] = p;
    }
}

// ---------- GEMM: C[M,N] = A[M,K] * B[N,K]^T, BM=64, swizzled LDS ----------
// MODE 2: +bias, relu, store bf16 AND fp32 (KSPLIT must be 1); MAP: scatter C rows via row_map
// MODE 3: fp32 partial store (split-K), no bias/act
template <int MODE, int BN, int KSPLIT, bool MAP>
__global__ __launch_bounds__(256, 2) void gemm64(
    const ushort* __restrict__ A, int lda,
    const ushort* __restrict__ B, int ldb,
    const float* __restrict__ bias,
    const int* __restrict__ row_map,
    ushort* __restrict__ Cb, float* __restrict__ Cf, int ldc,
    int K, size_t part_stride) {
    __shared__ __attribute__((aligned(16))) ushort sA[64 * 64];
    __shared__ __attribute__((aligned(16))) ushort sB[BN * 64];

    constexpr int NJ = (BN + 63) / 64;  // 16-col tiles per wave (2 for BN=128, 1 for BN=64)
    constexpr int UB = BN / 32;         // B units per wave

    const int tid = threadIdx.x;
    const int lane = tid & 63;
    const int w = tid >> 6;
    const int m0 = blockIdx.y * 64;
    const int n0 = blockIdx.x * BN;
    const int wn = w * (16 * NJ);
    const int nl = lane & 15;

    const int Kper = K / KSPLIT;
    const int kbase = (KSPLIT > 1) ? blockIdx.z * Kper : 0;
    if (MODE == 3) Cf += (size_t)blockIdx.z * part_stride;

    floatx4 acc[4][NJ] = {};

    for (int k0 = kbase; k0 < kbase + Kper; k0 += 64) {
#pragma unroll
        for (int u = 0; u < 2; ++u) {
            const int ua = w * 2 + u;
            stage_unit(A + (size_t)(m0 + ua * 8) * lda + k0, lda, &sA[ua * 512]);
        }
#pragma unroll
        for (int u = 0; u < UB; ++u) {
            const int ub = w * UB + u;
            stage_unit(B + (size_t)(n0 + ub * 8) * ldb + k0, ldb, &sB[ub * 512]);
        }
        __syncthreads();  // drains vmcnt per HIP barrier semantics
#pragma unroll
        for (int kk = 0; kk < 2; ++kk) {
            const int cb = kk * 32 + (lane >> 4) * 8;
            short8 a[4], b[NJ];
#pragma unroll
            for (int i = 0; i < 4; ++i) a[i] = lds_read8(sA, i * 16 + nl, cb);
#pragma unroll
            for (int j = 0; j < NJ; ++j) b[j] = lds_read8(sB, wn + j * 16 + nl, cb);
#pragma unroll
            for (int i = 0; i < 4; ++i)
#pragma unroll
                for (int j = 0; j < NJ; ++j)
                    acc[i][j] = __builtin_amdgcn_mfma_f32_16x16x32_bf16(a[i], b[j], acc[i][j], 0, 0, 0);
        }
        __syncthreads();
    }

    // epilogue: C/D layout row=(lane>>4)*4+reg, col=lane&15
    const int ml = (lane >> 4) * 4;
#pragma unroll
    for (int j = 0; j < NJ; ++j) {
        const int n = n0 + wn + j * 16 + nl;
        float bv = 0.0f;
        if (MODE == 2) bv = bias[n];
#pragma unroll
        for (int i = 0; i < 4; ++i) {
            const int mbase = m0 + i * 16 + ml;
#pragma unroll
            for (int r = 0; r < 4; ++r) {
                float v = acc[i][j][r];
                const int mr = mbase + r;
                const int orow = MAP ? row_map[mr] : mr;
                const size_t off = (size_t)orow * ldc + n;
                if (MODE == 2) {
                    v += bv; v = fmaxf(v, 0.0f);
                    Cb[off] = f2bf(v);
                    Cf[off] = v;
                } else {
                    Cf[off] = v;
                }
            }
        }
    }
}

// ---------- split-K combine: enc = relu(p0 + p1 + bias) -> bf16 ----------
__global__ __launch_bounds__(256) void combine_relu(const float* __restrict__ p0,
                                                    const float* __restrict__ p1,
                                                    const float* __restrict__ bias,
                                                    ushort* __restrict__ ob, int n4) {
    int i = blockIdx.x * blockDim.x + threadIdx.x;
    if (i >= n4) return;
    const float4 a = ((const float4*)p0)[i];
    const float4 b = ((const float4*)p1)[i];
    const int col = (i * 4) & 1023;
    const float4 bs = *(const float4*)(bias + col);
    ushort4 o;
    o.x = f2bf(fmaxf(a.x + b.x + bs.x, 0.f));
    o.y = f2bf(fmaxf(a.y + b.y + bs.y, 0.f));
    o.z = f2bf(fmaxf(a.z + b.z + bs.z, 0.f));
    o.w = f2bf(fmaxf(a.w + b.w + bs.w, 0.f));
    ((ushort4*)ob)[i] = o;
}

// ---------- fused GRU step in SORTED row space (verified round-0 structure) ----------
// Grid (8 col-slabs, 64 row-blocks). Block = 64 sorted rows x 64 h-cols, all gates.
// Rows sorted by cnt desc => active rows at step t are [0, nact[t]).
// Trims vs round-0 (both verified correct in R4/R5 runs):
//  - fully-inactive blocks RETURN (their rows are never staged by anyone again: active
//    blocks stage only their own panel; the boundary panel is active and republishes its
//    masked rows from the fp32 master hf every step)
//  - Hout store skipped at t=7 (never read; probs reads hf)
__global__ __launch_bounds__(256, 2) void gru_step(
    const ushort* __restrict__ Xall,  // nbr_b (orig row-major, row stride 4096), +t*512
    const ushort* __restrict__ Hin,   // [4096,512] bf16, sorted space
    const ushort* __restrict__ Wih,   // [1536,512] bf16
    const ushort* __restrict__ Whh,   // [1536,512] bf16
    const float* __restrict__ bih, const float* __restrict__ bhh,
    const int* __restrict__ perm, const int* __restrict__ nact,
    float* __restrict__ hf, ushort* __restrict__ Hout, int t) {
    __shared__ __attribute__((aligned(16))) ushort sX[64 * 64];     // 8 KB
    __shared__ __attribute__((aligned(16))) ushort sH[64 * 64];     // 8 KB
    __shared__ __attribute__((aligned(16))) ushort sBih[192 * 64];  // 24 KB
    __shared__ __attribute__((aligned(16))) ushort sBhh[192 * 64];  // 24 KB

    const int tid = threadIdx.x;
    const int lane = tid & 63;
    const int w = tid >> 6;
    const int s = blockIdx.x;        // col slab 0..7
    const int m0 = blockIdx.y * 64;  // sorted batch-row base
    const int na = nact[t];
    if (m0 >= na) return;            // fully inactive: rows never read downstream

    const int nl = lane & 15;
    const int ml = (lane >> 4) * 4;
    const int col = s * 64 + w * 16 + nl;  // this lane's h column

    // hoisted staging base pointers (constant across K-loop)
    const int r = lane >> 3;
    const int c = (lane & 7) ^ r;
    const ushort* X = Xall + t * 512;
    const ushort* xb[2];
    const ushort* hbp[2];
#pragma unroll
    for (int u = 0; u < 2; ++u) {
        const int srow = m0 + (w * 2 + u) * 8 + r;
        const int orig = perm[srow];
        xb[u] = X + (size_t)orig * 4096 + c * 8;
        hbp[u] = Hin + (size_t)srow * 512 + c * 8;
    }
    const ushort* wi[6];
    const ushort* wh[6];
#pragma unroll
    for (int j = 0; j < 6; ++j) {
        const int u = w * 6 + j;
        const int grow = (u >> 3) * 512 + s * 64 + (u & 7) * 8 + r;
        wi[j] = Wih + (size_t)grow * 512 + c * 8;
        wh[j] = Whh + (size_t)grow * 512 + c * 8;
    }

    // acc init with biases (depends only on column)
    floatx4 accr[4], accz[4], accn[4], acch[4];
    {
        const float br_ = bih[col] + bhh[col];
        const float bz_ = bih[512 + col] + bhh[512 + col];
        const float bn_i = bih[1024 + col];
        const float bn_h = bhh[1024 + col];
        const floatx4 vr = {br_, br_, br_, br_};
        const floatx4 vz = {bz_, bz_, bz_, bz_};
        const floatx4 vi = {bn_i, bn_i, bn_i, bn_i};
        const floatx4 vh = {bn_h, bn_h, bn_h, bn_h};
#pragma unroll
        for (int i = 0; i < 4; ++i) { accr[i] = vr; accz[i] = vz; accn[i] = vi; acch[i] = vh; }
    }

    for (int k0 = 0; k0 < 512; k0 += 64) {
#pragma unroll
        for (int u = 0; u < 2; ++u) {
            const int ua = w * 2 + u;
            load_lds16(xb[u] + k0, &sX[ua * 512]);
            load_lds16(hbp[u] + k0, &sH[ua * 512]);
        }
#pragma unroll
        for (int j = 0; j < 6; ++j) {
            const int u = w * 6 + j;
            load_lds16(wi[j] + k0, &sBih[u * 512]);
            load_lds16(wh[j] + k0, &sBhh[u * 512]);
        }
        __syncthreads();
#pragma unroll
        for (int kk = 0; kk < 2; ++kk) {
            const int cb = kk * 32 + (lane >> 4) * 8;
            short8 ax[4], ah[4];
#pragma unroll
            for (int i = 0; i < 4; ++i) {
                ax[i] = lds_read8(sX, i * 16 + nl, cb);
                ah[i] = lds_read8(sH, i * 16 + nl, cb);
            }
            const short8 bir = lds_read8(sBih, w * 16 + nl, cb);
            const short8 biz = lds_read8(sBih, 64 + w * 16 + nl, cb);
            const short8 bin = lds_read8(sBih, 128 + w * 16 + nl, cb);
            const short8 bhr = lds_read8(sBhh, w * 16 + nl, cb);
            const short8 bhz = lds_read8(sBhh, 64 + w * 16 + nl, cb);
            const short8 bhn = lds_read8(sBhh, 128 + w * 16 + nl, cb);
#pragma unroll
            for (int i = 0; i < 4; ++i) {
                accr[i] = __builtin_amdgcn_mfma_f32_16x16x32_bf16(ax[i], bir, accr[i], 0, 0, 0);
                accr[i] = __builtin_amdgcn_mfma_f32_16x16x32_bf16(ah[i], bhr, accr[i], 0, 0, 0);
                accz[i] = __builtin_amdgcn_mfma_f32_16x16x32_bf16(ax[i], biz, accz[i], 0, 0, 0);
                accz[i] = __builtin_amdgcn_mfma_f32_16x16x32_bf16(ah[i], bhz, accz[i], 0, 0, 0);
                accn[i] = __builtin_amdgcn_mfma_f32_16x16x32_bf16(ax[i], bin, accn[i], 0, 0, 0);
                acch[i] = __builtin_amdgcn_mfma_f32_16x16x32_bf16(ah[i], bhn, acch[i], 0, 0, 0);
            }
        }
        __syncthreads();
    }

    // epilogue: gates + positional mask (sorted rows)
    const bool full = (m0 + 64 <= na);
#pragma unroll
    for (int i = 0; i < 4; ++i) {
#pragma unroll
        for (int r4 = 0; r4 < 4; ++r4) {
            const int lr = i * 16 + ml + r4;
            const int row = m0 + lr;
            const float rg = fast_sigmoid(accr[i][r4]);
            const float zg = fast_sigmoid(accz[i][r4]);
            const float ng = fast_tanh(accn[i][r4] + rg * acch[i][r4]);
            const size_t off = (size_t)row * 512 + col;
            const float ho = hf[off];
            const bool act = full || (row < na);
            const float hv = act ? ((1.0f - zg) * ng + zg * ho) : ho;
            hf[off] = hv;
            if (t < 7) Hout[off] = f2bf(hv);
        }
    }
}

// ---------- v_net: tanh(enc @ W_v^T + b_v), one wave per row (original space) ----------
__global__ __launch_bounds__(256) void v_kernel(const ushort* __restrict__ enc,
                                                const float* __restrict__ Wv,
                                                const float* __restrict__ bv,
                                                float* __restrict__ out) {
    const int row = blockIdx.x * 4 + (threadIdx.x >> 6);
    const int lane = threadIdx.x & 63;
    const ushort* e = enc + (size_t)row * 1024;
    float s = 0.0f;
#pragma unroll
    for (int i = 0; i < 16; ++i) {
        int k = lane + i * 64;
        s += bf2f(e[k]) * Wv[k];
    }
#pragma unroll
    for (int off = 32; off; off >>= 1) s += __shfl_down(s, off, 64);
    if (lane == 0) out[row] = fast_tanh(s + bv[0]);
}

// ---------- to_probs: softmax(relu(h @ W_pr^T + b_pr)); h in sorted space ----------
__global__ __launch_bounds__(256) void probs_kernel(const float* __restrict__ h,
                                                    const float* __restrict__ Wpr,
                                                    const float* __restrict__ bpr,
                                                    const int* __restrict__ perm,
                                                    float* __restrict__ out) {
    const int srow = blockIdx.x * 4 + (threadIdx.x >> 6);
    const int lane = threadIdx.x & 63;
    const float* hr = h + (size_t)srow * 512;
    float p0 = 0.f, p1 = 0.f, p2 = 0.f;
#pragma unroll
    for (int i = 0; i < 8; ++i) {
        int k = lane + i * 64;
        float x = hr[k];
        p0 += x * Wpr[k];
        p1 += x * Wpr[512 + k];
        p2 += x * Wpr[1024 + k];
    }
#pragma unroll
    for (int off = 32; off; off >>= 1) {
        p0 += __shfl_down(p0, off, 64);
        p1 += __shfl_down(p1, off, 64);
        p2 += __shfl_down(p2, off, 64);
    }
    if (lane == 0) {
        const int orow = perm[srow];
        p0 = fmaxf(p0 + bpr[0], 0.f);
        p1 = fmaxf(p1 + bpr[1], 0.f);
        p2 = fmaxf(p2 + bpr[2], 0.f);
        float m = fmaxf(p0, fmaxf(p1, p2));
        float e0 = __expf(p0 - m), e1 = __expf(p1 - m), e2 = __expf(p2 - m);
        float inv = 1.0f / (e0 + e1 + e2);
        out[orow * 3 + 0] = e0 * inv;
        out[orow * 3 + 1] = e1 * inv;
        out[orow * 3 + 2] = e2 * inv;
    }
}

extern "C" void kernel_launch(void* const* d_in, const int* in_sizes, int n_in,
                              void* d_out, int out_size, void* d_ws, size_t ws_size,
                              hipStream_t stream) {
    const float* obs   = (const float*)d_in[0];   // [4096,4096]
    const float* nbr   = (const float*)d_in[1];   // [4096,8,512]
    const int*   cnt   = (const int*)d_in[2];     // [4096]
    const float* W_ds  = (const float*)d_in[3];   // [1024,4096]
    const float* b_ds  = (const float*)d_in[4];
    const float* W_pol = (const float*)d_in[5];   // [512,1024]
    const float* b_pol = (const float*)d_in[6];
    const float* W_v   = (const float*)d_in[7];   // [1,1024]
    const float* b_v   = (const float*)d_in[8];
    const float* W_ih  = (const float*)d_in[9];   // [1536,512]
    const float* b_ih  = (const float*)d_in[10];
    const float* W_hh  = (const float*)d_in[11];  // [1536,512]
    const float* b_hh  = (const float*)d_in[12];
    const float* W_pr  = (const float*)d_in[13];  // [3,512]
    const float* b_pr  = (const float*)d_in[14];
    float* out = (float*)d_out;  // [4096*3 probs][4096 state_vals]

    // workspace layout (round-0 footprint, ~100 MB + 32 KB)
    ushort* obs_b  = (ushort*)d_ws;              // 32 MB
    ushort* Wds_b  = obs_b + 16777216;           // 8 MB
    ushort* Wpol_b = Wds_b + 4194304;            // 1 MB
    ushort* Wih_b  = Wpol_b + 524288;            // 1.5 MB
    ushort* Whh_b  = Wih_b + 786432;             // 1.5 MB
    ushort* enc_b  = Whh_b + 786432;             // 8 MB
    ushort* h_b0   = enc_b + 4194304;            // 4 MB
    ushort* h_b1   = h_b0 + 2097152;             // 4 MB
    float*  h_f    = (float*)(h_b1 + 2097152);   // 8 MB
    float*  part   = h_f + 2097152;              // 32 MB split-K scratch, then nbr_b
    ushort* nbr_b  = (ushort*)part;              // aliases part AFTER combine
    int*    perm   = (int*)(part + 8388608);     // 4096
    int*    inv    = perm + 4096;                // 4096
    int*    nact   = inv + 4096;                 // 16

    // 0) sort rows by neighbor count (descending)
    sort_by_cnt<<<1, 256, 0, stream>>>(cnt, perm, inv, nact);

    // 1) one merged cvt for obs + all weights
    cvt_all<<<22528, 256, 0, stream>>>(obs, obs_b, W_ds, Wds_b, W_pol, Wpol_b,
                                       W_ih, Wih_b, W_hh, Whh_b);

    // 2) enc = relu(obs @ W_ds^T + b_ds), BN=128 split-K=2 -> 1024 blocks (~4/CU)
    gemm64<3, 128, 2, false><<<dim3(8, 64, 2), 256, 0, stream>>>(
        obs_b, 4096, Wds_b, 4096, nullptr, nullptr, nullptr, part, 1024, 4096, 4194304);
    combine_relu<<<4096, 256, 0, stream>>>(part, part + 4194304, b_ds, enc_b, 1048576);

    // 3) nbr -> bf16 into the (now free) split-K scratch
    cvt_f32_bf16<<<16384, 256, 0, stream>>>(nbr, nbr_b, 4194304);

    // 4) pol = relu(enc @ W_pol^T + b_pol) scattered into sorted space (h_b0 + h_f)
    gemm64<2, 64, 1, true><<<dim3(8, 64, 1), 256, 0, stream>>>(
        enc_b, 1024, Wpol_b, 1024, b_pol, inv, h_b0, h_f, 512, 1024, 0);

    // 5) state_vals (original space)
    v_kernel<<<1024, 256, 0, stream>>>(enc_b, W_v, b_v, out + 12288);

    // 6) GRU: 8 fused steps in sorted space (verified fat-LDS structure), h bf16 ping-pong,
    //    hf in-place fp32 master
    for (int t = 0; t < 8; ++t) {
        const ushort* hin = (t & 1) ? h_b1 : h_b0;
        ushort* hout = (t & 1) ? h_b0 : h_b1;
        gru_step<<<dim3(8, 64), 256, 0, stream>>>(nbr_b, hin, Wih_b, Whh_b,
                                                  b_ih, b_hh, perm, nact, h_f, hout, t);
    }

    // 7) probs (sorted -> original scatter)
    probs_kernel<<<1024, 256, 0, stream>>>(h_f, W_pr, b_pr, perm, out);
}

// Round 7
// 435.013 us; speedup vs baseline: 1.4612x; 1.0193x over previous
//
#include <hip/hip_runtime.h>
#include <hip/hip_bf16.h>

// ---------- common helpers ----------
typedef __attribute__((ext_vector_type(8))) short short8;
typedef __attribute__((ext_vector_type(4))) float floatx4;

__device__ __forceinline__ ushort f2bf(float x) {
    unsigned u = __float_as_uint(x);
    unsigned r = (u + 0x7fffu + ((u >> 16) & 1u)) >> 16;
    return (ushort)r;
}
__device__ __forceinline__ float bf2f(ushort h) {
    return __uint_as_float(((unsigned)h) << 16);
}
__device__ __forceinline__ float fast_sigmoid(float x) {
    return 1.0f / (1.0f + __expf(-x));
}
__device__ __forceinline__ float fast_tanh(float x) {
    x = fminf(fmaxf(x, -15.0f), 15.0f);
    float e = __expf(2.0f * x);
    return (e - 1.0f) / (e + 1.0f);
}
__device__ __forceinline__ void load_lds16(const void* g, void* l) {
    __builtin_amdgcn_global_load_lds(
        (__attribute__((address_space(1))) void*)(g),
        (__attribute__((address_space(3))) void*)(l),
        16, 0, 0);
}

// ---------- swizzled LDS tile: units of 8 rows x 64 cols (1 KB) ----------
// Physical: unit row r holds logical 16B-chunk lc at chunk slot lc^r (conflict-free, verified:
// SQ_LDS_BANK_CONFLICT=0). Staging lane L = r*8+cp fetches logical chunk cp^r.
__device__ __forceinline__ void stage_unit(const ushort* grow0, int ld, ushort* lds_unit) {
    const int lane = threadIdx.x & 63;
    const int r = lane >> 3;
    const int c = (lane & 7) ^ r;
    load_lds16(grow0 + (size_t)r * ld + c * 8, lds_unit);
}
__device__ __forceinline__ short8 lds_read8(const ushort* buf, int R, int c_el) {
    const int idx = ((R >> 3) << 9) + ((R & 7) << 6) + ((((c_el >> 3) ^ (R & 7))) << 3);
    return *(const short8*)(buf + idx);
}

// ---------- fp32 -> bf16: one merged kernel for obs + 4 weight tensors ----------
__global__ __launch_bounds__(256) void cvt_all(
    const float* __restrict__ s0, ushort* __restrict__ d0,   // obs   4194304 float4
    const float* __restrict__ s1, ushort* __restrict__ d1,   // W_ds  1048576
    const float* __restrict__ s2, ushort* __restrict__ d2,   // W_pol  131072
    const float* __restrict__ s3, ushort* __restrict__ d3,   // W_ih   196608
    const float* __restrict__ s4, ushort* __restrict__ d4) { // W_hh   196608
    int i = blockIdx.x * 256 + threadIdx.x;
    const float* s;
    ushort* d;
    int j;
    if (i < 4194304)      { s = s0; d = d0; j = i; }
    else if (i < 5242880) { s = s1; d = d1; j = i - 4194304; }
    else if (i < 5373952) { s = s2; d = d2; j = i - 5242880; }
    else if (i < 5570560) { s = s3; d = d3; j = i - 5373952; }
    else if (i < 5767168) { s = s4; d = d4; j = i - 5570560; }
    else return;
    const float4 v = ((const float4*)s)[j];
    ushort4 o;
    o.x = f2bf(v.x); o.y = f2bf(v.y); o.z = f2bf(v.z); o.w = f2bf(v.w);
    ((ushort4*)d)[j] = o;
}

// ---------- plain fp32 -> bf16 (for nbr, converted late into split-K scratch) ----------
__global__ __launch_bounds__(256) void cvt_f32_bf16(const float* __restrict__ src,
                                                    ushort* __restrict__ dst, int n4) {
    int i = blockIdx.x * blockDim.x + threadIdx.x;
    if (i >= n4) return;
    const float4 v = ((const float4*)src)[i];
    ushort4 o;
    o.x = f2bf(v.x); o.y = f2bf(v.y); o.z = f2bf(v.z); o.w = f2bf(v.w);
    ((ushort4*)dst)[i] = o;
}

// ---------- counting sort of rows by cnt descending ----------
// perm[sorted]=orig, inv[orig]=sorted, nact[t]=#rows with cnt>t.
__global__ __launch_bounds__(256) void sort_by_cnt(const int* __restrict__ cnt,
                                                   int* __restrict__ perm,
                                                   int* __restrict__ inv,
                                                   int* __restrict__ nact) {
    __shared__ int h[9];
    __shared__ int cur[9];
    const int tid = threadIdx.x;
    if (tid < 9) h[tid] = 0;
    __syncthreads();
    for (int i = tid; i < 4096; i += 256) atomicAdd(&h[cnt[i]], 1);
    __syncthreads();
    if (tid == 0) {
        int off = 0;
        for (int c = 8; c >= 0; --c) { cur[c] = off; off += h[c]; }
        for (int t = 0; t < 8; ++t) {
            int n = 0;
            for (int c = t + 1; c <= 8; ++c) n += h[c];
            nact[t] = n;
        }
    }
    __syncthreads();
    for (int i = tid; i < 4096; i += 256) {
        const int c = cnt[i];
        const int p = atomicAdd(&cur[c], 1);
        perm[p] = i;
        inv[i] = p;
    }
}

// ---------- GEMM: C[M,N] = A[M,K] * B[N,K]^T, BM=64, swizzled LDS ----------
// MODE 2: +bias, relu, store bf16 AND fp32 (KSPLIT must be 1); MAP: scatter C rows via row_map
// MODE 3: fp32 partial store (split-K), no bias/act
// SWZ: XCD-chunk swizzle within each z-plane (plane size %8==0): XCD k gets 8 consecutive
// m-panels x all n-panels -> its A m-chunk (2 MB at K=2048) is fetched once into one L2.
// Mechanism verified R1 (FETCH 135->49 MB); combined with split-K here to keep 4 blocks/CU.
template <int MODE, int BN, int KSPLIT, bool MAP, bool SWZ>
__global__ __launch_bounds__(256, 2) void gemm64(
    const ushort* __restrict__ A, int lda,
    const ushort* __restrict__ B, int ldb,
    const float* __restrict__ bias,
    const int* __restrict__ row_map,
    ushort* __restrict__ Cb, float* __restrict__ Cf, int ldc,
    int K, size_t part_stride) {
    __shared__ __attribute__((aligned(16))) ushort sA[64 * 64];
    __shared__ __attribute__((aligned(16))) ushort sB[BN * 64];

    constexpr int NJ = (BN + 63) / 64;  // 16-col tiles per wave (2 for BN=128, 1 for BN=64)
    constexpr int UB = BN / 32;         // B units per wave

    int bx = blockIdx.x, by = blockIdx.y;
    if (SWZ) {
        const int nwg = gridDim.x * gridDim.y;
        const int b = by * gridDim.x + bx;
        const int f = (b & 7) * (nwg >> 3) + (b >> 3);
        bx = f % gridDim.x;
        by = f / gridDim.x;
    }

    const int tid = threadIdx.x;
    const int lane = tid & 63;
    const int w = tid >> 6;
    const int m0 = by * 64;
    const int n0 = bx * BN;
    const int wn = w * (16 * NJ);
    const int nl = lane & 15;

    const int Kper = K / KSPLIT;
    const int kbase = (KSPLIT > 1) ? blockIdx.z * Kper : 0;
    if (MODE == 3) Cf += (size_t)blockIdx.z * part_stride;

    floatx4 acc[4][NJ] = {};

    for (int k0 = kbase; k0 < kbase + Kper; k0 += 64) {
#pragma unroll
        for (int u = 0; u < 2; ++u) {
            const int ua = w * 2 + u;
            stage_unit(A + (size_t)(m0 + ua * 8) * lda + k0, lda, &sA[ua * 512]);
        }
#pragma unroll
        for (int u = 0; u < UB; ++u) {
            const int ub = w * UB + u;
            stage_unit(B + (size_t)(n0 + ub * 8) * ldb + k0, ldb, &sB[ub * 512]);
        }
        __syncthreads();  // drains vmcnt per HIP barrier semantics
#pragma unroll
        for (int kk = 0; kk < 2; ++kk) {
            const int cb = kk * 32 + (lane >> 4) * 8;
            short8 a[4], b[NJ];
#pragma unroll
            for (int i = 0; i < 4; ++i) a[i] = lds_read8(sA, i * 16 + nl, cb);
#pragma unroll
            for (int j = 0; j < NJ; ++j) b[j] = lds_read8(sB, wn + j * 16 + nl, cb);
#pragma unroll
            for (int i = 0; i < 4; ++i)
#pragma unroll
                for (int j = 0; j < NJ; ++j)
                    acc[i][j] = __builtin_amdgcn_mfma_f32_16x16x32_bf16(a[i], b[j], acc[i][j], 0, 0, 0);
        }
        __syncthreads();
    }

    // epilogue: C/D layout row=(lane>>4)*4+reg, col=lane&15
    const int ml = (lane >> 4) * 4;
#pragma unroll
    for (int j = 0; j < NJ; ++j) {
        const int n = n0 + wn + j * 16 + nl;
        float bv = 0.0f;
        if (MODE == 2) bv = bias[n];
#pragma unroll
        for (int i = 0; i < 4; ++i) {
            const int mbase = m0 + i * 16 + ml;
#pragma unroll
            for (int r = 0; r < 4; ++r) {
                float v = acc[i][j][r];
                const int mr = mbase + r;
                const int orow = MAP ? row_map[mr] : mr;
                const size_t off = (size_t)orow * ldc + n;
                if (MODE == 2) {
                    v += bv; v = fmaxf(v, 0.0f);
                    Cb[off] = f2bf(v);
                    Cf[off] = v;
                } else {
                    Cf[off] = v;
                }
            }
        }
    }
}

// ---------- split-K combine: enc = relu(p0 + p1 + bias) -> bf16 ----------
__global__ __launch_bounds__(256) void combine_relu(const float* __restrict__ p0,
                                                    const float* __restrict__ p1,
                                                    const float* __restrict__ bias,
                                                    ushort* __restrict__ ob, int n4) {
    int i = blockIdx.x * blockDim.x + threadIdx.x;
    if (i >= n4) return;
    const float4 a = ((const float4*)p0)[i];
    const float4 b = ((const float4*)p1)[i];
    const int col = (i * 4) & 1023;
    const float4 bs = *(const float4*)(bias + col);
    ushort4 o;
    o.x = f2bf(fmaxf(a.x + b.x + bs.x, 0.f));
    o.y = f2bf(fmaxf(a.y + b.y + bs.y, 0.f));
    o.z = f2bf(fmaxf(a.z + b.z + bs.z, 0.f));
    o.w = f2bf(fmaxf(a.w + b.w + bs.w, 0.f));
    ((ushort4*)ob)[i] = o;
}

// ---------- fused GRU step in SORTED row space (verified fat-LDS structure) ----------
// Grid (8,64) = 512 blocks. PANEL-GROUPED XCD remap: wgid = by*8+bx; s = wgid/64,
// panel = wgid%64 -> the 8 slab-blocks of panel p have wgid === p (mod 8) => land on ONE
// XCD (round-robin dispatch). Per-XCD working set = ~7 panels' X/H (0.9 MB) + all weights
// (3 MB) < 4 MB L2, and each X/H panel gets 8x L2 reuse (previously 0x: each XCD streamed
// ALL panels' X/H as compulsory L2 misses). Pure index remap: numerics/sync unchanged.
__global__ __launch_bounds__(256, 2) void gru_step(
    const ushort* __restrict__ Xall,  // nbr_b (orig row-major, row stride 4096), +t*512
    const ushort* __restrict__ Hin,   // [4096,512] bf16, sorted space
    const ushort* __restrict__ Wih,   // [1536,512] bf16
    const ushort* __restrict__ Whh,   // [1536,512] bf16
    const float* __restrict__ bih, const float* __restrict__ bhh,
    const int* __restrict__ perm, const int* __restrict__ nact,
    float* __restrict__ hf, ushort* __restrict__ Hout, int t) {
    __shared__ __attribute__((aligned(16))) ushort sX[64 * 64];     // 8 KB
    __shared__ __attribute__((aligned(16))) ushort sH[64 * 64];     // 8 KB
    __shared__ __attribute__((aligned(16))) ushort sBih[192 * 64];  // 24 KB
    __shared__ __attribute__((aligned(16))) ushort sBhh[192 * 64];  // 24 KB

    const int tid = threadIdx.x;
    const int lane = tid & 63;
    const int w = tid >> 6;
    const int wgid = blockIdx.y * 8 + blockIdx.x;  // dispatch-linear id
    const int s = wgid >> 6;         // col slab 0..7
    const int m0 = (wgid & 63) * 64; // sorted batch-row base (panel-grouped per XCD)
    const int na = nact[t];
    if (m0 >= na) return;            // fully inactive: rows never read downstream

    const int nl = lane & 15;
    const int ml = (lane >> 4) * 4;
    const int col = s * 64 + w * 16 + nl;  // this lane's h column

    // hoisted staging base pointers (constant across K-loop)
    const int r = lane >> 3;
    const int c = (lane & 7) ^ r;
    const ushort* X = Xall + t * 512;
    const ushort* xb[2];
    const ushort* hbp[2];
#pragma unroll
    for (int u = 0; u < 2; ++u) {
        const int srow = m0 + (w * 2 + u) * 8 + r;
        const int orig = perm[srow];
        xb[u] = X + (size_t)orig * 4096 + c * 8;
        hbp[u] = Hin + (size_t)srow * 512 + c * 8;
    }
    const ushort* wi[6];
    const ushort* wh[6];
#pragma unroll
    for (int j = 0; j < 6; ++j) {
        const int u = w * 6 + j;
        const int grow = (u >> 3) * 512 + s * 64 + (u & 7) * 8 + r;
        wi[j] = Wih + (size_t)grow * 512 + c * 8;
        wh[j] = Whh + (size_t)grow * 512 + c * 8;
    }

    // acc init with biases (depends only on column)
    floatx4 accr[4], accz[4], accn[4], acch[4];
    {
        const float br_ = bih[col] + bhh[col];
        const float bz_ = bih[512 + col] + bhh[512 + col];
        const float bn_i = bih[1024 + col];
        const float bn_h = bhh[1024 + col];
        const floatx4 vr = {br_, br_, br_, br_};
        const floatx4 vz = {bz_, bz_, bz_, bz_};
        const floatx4 vi = {bn_i, bn_i, bn_i, bn_i};
        const floatx4 vh = {bn_h, bn_h, bn_h, bn_h};
#pragma unroll
        for (int i = 0; i < 4; ++i) { accr[i] = vr; accz[i] = vz; accn[i] = vi; acch[i] = vh; }
    }

    for (int k0 = 0; k0 < 512; k0 += 64) {
#pragma unroll
        for (int u = 0; u < 2; ++u) {
            const int ua = w * 2 + u;
            load_lds16(xb[u] + k0, &sX[ua * 512]);
            load_lds16(hbp[u] + k0, &sH[ua * 512]);
        }
#pragma unroll
        for (int j = 0; j < 6; ++j) {
            const int u = w * 6 + j;
            load_lds16(wi[j] + k0, &sBih[u * 512]);
            load_lds16(wh[j] + k0, &sBhh[u * 512]);
        }
        __syncthreads();
#pragma unroll
        for (int kk = 0; kk < 2; ++kk) {
            const int cb = kk * 32 + (lane >> 4) * 8;
            short8 ax[4], ah[4];
#pragma unroll
            for (int i = 0; i < 4; ++i) {
                ax[i] = lds_read8(sX, i * 16 + nl, cb);
                ah[i] = lds_read8(sH, i * 16 + nl, cb);
            }
            const short8 bir = lds_read8(sBih, w * 16 + nl, cb);
            const short8 biz = lds_read8(sBih, 64 + w * 16 + nl, cb);
            const short8 bin = lds_read8(sBih, 128 + w * 16 + nl, cb);
            const short8 bhr = lds_read8(sBhh, w * 16 + nl, cb);
            const short8 bhz = lds_read8(sBhh, 64 + w * 16 + nl, cb);
            const short8 bhn = lds_read8(sBhh, 128 + w * 16 + nl, cb);
#pragma unroll
            for (int i = 0; i < 4; ++i) {
                accr[i] = __builtin_amdgcn_mfma_f32_16x16x32_bf16(ax[i], bir, accr[i], 0, 0, 0);
                accr[i] = __builtin_amdgcn_mfma_f32_16x16x32_bf16(ah[i], bhr, accr[i], 0, 0, 0);
                accz[i] = __builtin_amdgcn_mfma_f32_16x16x32_bf16(ax[i], biz, accz[i], 0, 0, 0);
                accz[i] = __builtin_amdgcn_mfma_f32_16x16x32_bf16(ah[i], bhz, accz[i], 0, 0, 0);
                accn[i] = __builtin_amdgcn_mfma_f32_16x16x32_bf16(ax[i], bin, accn[i], 0, 0, 0);
                acch[i] = __builtin_amdgcn_mfma_f32_16x16x32_bf16(ah[i], bhn, acch[i], 0, 0, 0);
            }
        }
        __syncthreads();
    }

    // epilogue: gates + positional mask (sorted rows)
    const bool full = (m0 + 64 <= na);
#pragma unroll
    for (int i = 0; i < 4; ++i) {
#pragma unroll
        for (int r4 = 0; r4 < 4; ++r4) {
            const int lr = i * 16 + ml + r4;
            const int row = m0 + lr;
            const float rg = fast_sigmoid(accr[i][r4]);
            const float zg = fast_sigmoid(accz[i][r4]);
            const float ng = fast_tanh(accn[i][r4] + rg * acch[i][r4]);
            const size_t off = (size_t)row * 512 + col;
            const float ho = hf[off];
            const bool act = full || (row < na);
            const float hv = act ? ((1.0f - zg) * ng + zg * ho) : ho;
            hf[off] = hv;
            if (t < 7) Hout[off] = f2bf(hv);
        }
    }
}

// ---------- v_net: tanh(enc @ W_v^T + b_v), one wave per row (original space) ----------
__global__ __launch_bounds__(256) void v_kernel(const ushort* __restrict__ enc,
                                                const float* __restrict__ Wv,
                                                const float* __restrict__ bv,
                                                float* __restrict__ out) {
    const int row = blockIdx.x * 4 + (threadIdx.x >> 6);
    const int lane = threadIdx.x & 63;
    const ushort* e = enc + (size_t)row * 1024;
    float s = 0.0f;
#pragma unroll
    for (int i = 0; i < 16; ++i) {
        int k = lane + i * 64;
        s += bf2f(e[k]) * Wv[k];
    }
#pragma unroll
    for (int off = 32; off; off >>= 1) s += __shfl_down(s, off, 64);
    if (lane == 0) out[row] = fast_tanh(s + bv[0]);
}

// ---------- to_probs: softmax(relu(h @ W_pr^T + b_pr)); h in sorted space ----------
__global__ __launch_bounds__(256) void probs_kernel(const float* __restrict__ h,
                                                    const float* __restrict__ Wpr,
                                                    const float* __restrict__ bpr,
                                                    const int* __restrict__ perm,
                                                    float* __restrict__ out) {
    const int srow = blockIdx.x * 4 + (threadIdx.x >> 6);
    const int lane = threadIdx.x & 63;
    const float* hr = h + (size_t)srow * 512;
    float p0 = 0.f, p1 = 0.f, p2 = 0.f;
#pragma unroll
    for (int i = 0; i < 8; ++i) {
        int k = lane + i * 64;
        float x = hr[k];
        p0 += x * Wpr[k];
        p1 += x * Wpr[512 + k];
        p2 += x * Wpr[1024 + k];
    }
#pragma unroll
    for (int off = 32; off; off >>= 1) {
        p0 += __shfl_down(p0, off, 64);
        p1 += __shfl_down(p1, off, 64);
        p2 += __shfl_down(p2, off, 64);
    }
    if (lane == 0) {
        const int orow = perm[srow];
        p0 = fmaxf(p0 + bpr[0], 0.f);
        p1 = fmaxf(p1 + bpr[1], 0.f);
        p2 = fmaxf(p2 + bpr[2], 0.f);
        float m = fmaxf(p0, fmaxf(p1, p2));
        float e0 = __expf(p0 - m), e1 = __expf(p1 - m), e2 = __expf(p2 - m);
        float inv = 1.0f / (e0 + e1 + e2);
        out[orow * 3 + 0] = e0 * inv;
        out[orow * 3 + 1] = e1 * inv;
        out[orow * 3 + 2] = e2 * inv;
    }
}

extern "C" void kernel_launch(void* const* d_in, const int* in_sizes, int n_in,
                              void* d_out, int out_size, void* d_ws, size_t ws_size,
                              hipStream_t stream) {
    const float* obs   = (const float*)d_in[0];   // [4096,4096]
    const float* nbr   = (const float*)d_in[1];   // [4096,8,512]
    const int*   cnt   = (const int*)d_in[2];     // [4096]
    const float* W_ds  = (const float*)d_in[3];   // [1024,4096]
    const float* b_ds  = (const float*)d_in[4];
    const float* W_pol = (const float*)d_in[5];   // [512,1024]
    const float* b_pol = (const float*)d_in[6];
    const float* W_v   = (const float*)d_in[7];   // [1,1024]
    const float* b_v   = (const float*)d_in[8];
    const float* W_ih  = (const float*)d_in[9];   // [1536,512]
    const float* b_ih  = (const float*)d_in[10];
    const float* W_hh  = (const float*)d_in[11];  // [1536,512]
    const float* b_hh  = (const float*)d_in[12];
    const float* W_pr  = (const float*)d_in[13];  // [3,512]
    const float* b_pr  = (const float*)d_in[14];
    float* out = (float*)d_out;  // [4096*3 probs][4096 state_vals]

    // workspace layout (round-0 footprint, ~100 MB + 32 KB)
    ushort* obs_b  = (ushort*)d_ws;              // 32 MB
    ushort* Wds_b  = obs_b + 16777216;           // 8 MB
    ushort* Wpol_b = Wds_b + 4194304;            // 1 MB
    ushort* Wih_b  = Wpol_b + 524288;            // 1.5 MB
    ushort* Whh_b  = Wih_b + 786432;             // 1.5 MB
    ushort* enc_b  = Whh_b + 786432;             // 8 MB
    ushort* h_b0   = enc_b + 4194304;            // 4 MB
    ushort* h_b1   = h_b0 + 2097152;             // 4 MB
    float*  h_f    = (float*)(h_b1 + 2097152);   // 8 MB
    float*  part   = h_f + 2097152;              // 32 MB split-K scratch, then nbr_b
    ushort* nbr_b  = (ushort*)part;              // aliases part AFTER combine
    int*    perm   = (int*)(part + 8388608);     // 4096
    int*    inv    = perm + 4096;                // 4096
    int*    nact   = inv + 4096;                 // 16

    // 0) sort rows by neighbor count (descending)
    sort_by_cnt<<<1, 256, 0, stream>>>(cnt, perm, inv, nact);

    // 1) one merged cvt for obs + all weights
    cvt_all<<<22528, 256, 0, stream>>>(obs, obs_b, W_ds, Wds_b, W_pol, Wpol_b,
                                       W_ih, Wih_b, W_hh, Whh_b);

    // 2) enc = relu(obs @ W_ds^T + b_ds), BN=128 split-K=2 (1024 blocks, 4/CU)
    //    + XCD-chunk swizzle per z-plane (A chunk L2-resident per XCD)
    gemm64<3, 128, 2, false, true><<<dim3(8, 64, 2), 256, 0, stream>>>(
        obs_b, 4096, Wds_b, 4096, nullptr, nullptr, nullptr, part, 1024, 4096, 4194304);
    combine_relu<<<4096, 256, 0, stream>>>(part, part + 4194304, b_ds, enc_b, 1048576);

    // 3) nbr -> bf16 into the (now free) split-K scratch
    cvt_f32_bf16<<<16384, 256, 0, stream>>>(nbr, nbr_b, 4194304);

    // 4) pol = relu(enc @ W_pol^T + b_pol) scattered into sorted space (h_b0 + h_f),
    //    same XCD swizzle (512 blocks, %8==0)
    gemm64<2, 64, 1, true, true><<<dim3(8, 64, 1), 256, 0, stream>>>(
        enc_b, 1024, Wpol_b, 1024, b_pol, inv, h_b0, h_f, 512, 1024, 0);

    // 5) state_vals (original space)
    v_kernel<<<1024, 256, 0, stream>>>(enc_b, W_v, b_v, out + 12288);

    // 6) GRU: 8 fused steps in sorted space (fat-LDS structure), panel-grouped XCD remap,
    //    h bf16 ping-pong, hf in-place fp32 master
    for (int t = 0; t < 8; ++t) {
        const ushort* hin = (t & 1) ? h_b1 : h_b0;
        ushort* hout = (t & 1) ? h_b0 : h_b1;
        gru_step<<<dim3(8, 64), 256, 0, stream>>>(nbr_b, hin, Wih_b, Whh_b,
                                                  b_ih, b_hh, perm, nact, h_f, hout, t);
    }

    // 7) probs (sorted -> original scatter)
    probs_kernel<<<1024, 256, 0, stream>>>(h_f, W_pr, b_pr, perm, out);
}